// Round 7
// baseline (190.325 us; speedup 1.0000x reference)
//
#include <hip/hip_runtime.h>
#include <hip/hip_bf16.h>

typedef short short8 __attribute__((ext_vector_type(8)));
typedef short short4v __attribute__((ext_vector_type(4)));
typedef float f32x4 __attribute__((ext_vector_type(4)));

#define E 256
#define DH 128

__device__ __forceinline__ float bf2f(__hip_bfloat16 x) { return __bfloat162float(x); }
__device__ __forceinline__ __hip_bfloat16 f2bf(float x) { return __float2bfloat16(x); }

__device__ __forceinline__ short8 cvt8(float4 a, float4 b) {
    __hip_bfloat16 t[8] = {f2bf(a.x), f2bf(a.y), f2bf(a.z), f2bf(a.w),
                           f2bf(b.x), f2bf(b.y), f2bf(b.z), f2bf(b.w)};
    return *reinterpret_cast<const short8*>(t);
}

// ---------- fused fp32 -> bf16 convert (edge + 4 weight arrays) ----------
struct CvtArgs { const float* in[5]; __hip_bfloat16* out[5]; int n[5]; };

__global__ __launch_bounds__(256) void f2b_all(CvtArgs a)
{
    int seg = blockIdx.y;
    int i = (blockIdx.x * 256 + threadIdx.x) * 8;
    if (i >= a.n[seg]) return;
    const float* in = a.in[seg];
    float4 x = *reinterpret_cast<const float4*>(in + i);
    float4 y = *reinterpret_cast<const float4*>(in + i + 4);
    *reinterpret_cast<short8*>(a.out[seg] + i) = cvt8(x, y);
}

// ---------- projection GEMM: out[M,256] = A[M,256] @ W^T + b (A fp32 or bf16) ----------
struct ProjSeg { const float* Af; const __hip_bfloat16* Ab;
                 const __hip_bfloat16* W; const float* b; __hip_bfloat16* out; };
struct ProjArgs { ProjSeg seg[5]; };

__global__ __launch_bounds__(256) void gemm_proj(ProjArgs args, int M)
{
    int wv = threadIdx.x >> 6, lane = threadIdx.x & 63;
    int m0 = blockIdx.x * 32;
    if (m0 >= M) return;
    ProjSeg sg = args.seg[blockIdx.y];
    int lo = lane & 15, hi = lane >> 4;

    const __hip_bfloat16* brow = sg.W + (size_t)(wv * 64 + lo) * E + hi * 8;

    f32x4 acc[2][4] = {};
    if (sg.Af) {
        const float* ar0 = sg.Af + (size_t)(m0 + lo) * E + hi * 8;
        const float* ar1 = ar0 + 16 * E;
#pragma unroll
        for (int k = 0; k < 8; ++k) {
            short8 a0 = cvt8(*reinterpret_cast<const float4*>(ar0 + k * 32),
                             *reinterpret_cast<const float4*>(ar0 + k * 32 + 4));
            short8 a1 = cvt8(*reinterpret_cast<const float4*>(ar1 + k * 32),
                             *reinterpret_cast<const float4*>(ar1 + k * 32 + 4));
#pragma unroll
            for (int nt = 0; nt < 4; ++nt) {
                short8 b = *reinterpret_cast<const short8*>(brow + (size_t)nt * 16 * E + k * 32);
                acc[0][nt] = __builtin_amdgcn_mfma_f32_16x16x32_bf16(a0, b, acc[0][nt], 0, 0, 0);
                acc[1][nt] = __builtin_amdgcn_mfma_f32_16x16x32_bf16(a1, b, acc[1][nt], 0, 0, 0);
            }
        }
    } else {
        const __hip_bfloat16* ar0 = sg.Ab + (size_t)(m0 + lo) * E + hi * 8;
        const __hip_bfloat16* ar1 = ar0 + 16 * E;
#pragma unroll
        for (int k = 0; k < 8; ++k) {
            short8 a0 = *reinterpret_cast<const short8*>(ar0 + k * 32);
            short8 a1 = *reinterpret_cast<const short8*>(ar1 + k * 32);
#pragma unroll
            for (int nt = 0; nt < 4; ++nt) {
                short8 b = *reinterpret_cast<const short8*>(brow + (size_t)nt * 16 * E + k * 32);
                acc[0][nt] = __builtin_amdgcn_mfma_f32_16x16x32_bf16(a0, b, acc[0][nt], 0, 0, 0);
                acc[1][nt] = __builtin_amdgcn_mfma_f32_16x16x32_bf16(a1, b, acc[1][nt], 0, 0, 0);
            }
        }
    }
#pragma unroll
    for (int nt = 0; nt < 4; ++nt) {
        int col = wv * 64 + nt * 16 + lo;
        float bias = sg.b[col];
#pragma unroll
        for (int mt = 0; mt < 2; ++mt)
#pragma unroll
            for (int r = 0; r < 4; ++r) {
                int row = m0 + mt * 16 + hi * 4 + r;
                sg.out[(size_t)row * E + col] = f2bf(acc[mt][nt][r] + bias);
            }
    }
}

// ---------- fused: sparse attn (16 faces) -> LDS tile -> outproj MFMA (reg) -> LN ----------
// 512 threads = 8 waves. Attention: 2 faces/wave. Outproj: wave w -> cols [w*32,w*32+32).
// LN via cross-wave partial sums (1 KB LDS), values stay in registers.
__global__ __launch_bounds__(512, 4) void attn_outproj_ln(
    const int* __restrict__ rel, const __hip_bfloat16* __restrict__ q16,
    const __hip_bfloat16* __restrict__ k16, const __hip_bfloat16* __restrict__ v16,
    const __hip_bfloat16* __restrict__ wout, const float* __restrict__ bout,
    const float* __restrict__ resid, const float* __restrict__ lng, const float* __restrict__ lnb,
    float* __restrict__ outp, int L, int ML)
{
    __shared__ __align__(16) __hip_bfloat16 atile[16 * 264];  // stride 264: 2-way banks (free)
    __shared__ __align__(16) float lds_w[16][2][16];          // [face][head][edge]
    __shared__ int lds_idx[16][16];
    __shared__ float lds_s[16][8], lds_s2[16][8];             // [row][wave]
    __shared__ float lds_mv[16], lds_rs[16];

    int tid = threadIdx.x, wv = tid >> 6, lane = tid & 63;
    int m0 = blockIdx.x * 16;
    int g = lane >> 2, q = lane & 3;
    const float scale = 0.088388347648318447f;  // 1/sqrt(128)

#pragma unroll
    for (int it = 0; it < 2; ++it) {
        int r = wv * 2 + it;          // local face row 0..15
        int face = m0 + r;
        const int* rr = rel + (size_t)face * ML;
        int myidx = (g < ML) ? rr[g] : -1;

        bool dup = false;
#pragma unroll
        for (int d = 1; d < 16; ++d) {
            int other = __shfl(myidx, ((g - d) & 15) * 4 + q);
            if (d <= g && other == myidx) dup = true;
        }
        bool myuse = (myidx >= 0) && !dup;   // set semantics: unique valid edges
        int safe = myidx < 0 ? 0 : myidx;
        if (q == 0) lds_idx[r][g] = safe;

#pragma unroll
        for (int h = 0; h < 2; ++h) {
            const __hip_bfloat16* kbase = k16 + (size_t)safe * E + h * DH;
            const __hip_bfloat16* qbase = q16 + (size_t)face * E + h * DH;
            float part = 0.f;
#pragma unroll
            for (int t = 0; t < 4; ++t) {
                short8 qv = *reinterpret_cast<const short8*>(qbase + (t * 4 + q) * 8);
                short8 kv = *reinterpret_cast<const short8*>(kbase + (t * 4 + q) * 8);
                const __hip_bfloat16* qp = (const __hip_bfloat16*)&qv;
                const __hip_bfloat16* kp = (const __hip_bfloat16*)&kv;
#pragma unroll
                for (int e2 = 0; e2 < 8; ++e2)
                    part += bf2f(qp[e2]) * bf2f(kp[e2]);
            }
            part += __shfl_xor(part, 1);
            part += __shfl_xor(part, 2);      // full 128-dim dot in all 4 quad lanes
            float sc = myuse ? part * scale : -1e30f;
            float mx = sc;
#pragma unroll
            for (int off = 4; off < 64; off <<= 1) mx = fmaxf(mx, __shfl_xor(mx, off));
            float e = __expf(sc - mx);        // exactly 0 for dead slots
            float den = e;
#pragma unroll
            for (int off = 4; off < 64; off <<= 1) den += __shfl_xor(den, off);
            if (q == 0) lds_w[r][h][g] = e / den;
        }

        // V phase: lane covers dims [4*lane, 4*lane+4)
        {
            int h = lane >> 5;
            float a0 = 0.f, a1 = 0.f, a2 = 0.f, a3 = 0.f;
#pragma unroll
            for (int j = 0; j < 16; ++j) {
                int ij = lds_idx[r][j];
                float wj = lds_w[r][h][j];    // 0 for unused edges
                short4v vv = *reinterpret_cast<const short4v*>(v16 + (size_t)ij * E + 4 * lane);
                const __hip_bfloat16* vp = (const __hip_bfloat16*)&vv;
                a0 += wj * bf2f(vp[0]);
                a1 += wj * bf2f(vp[1]);
                a2 += wj * bf2f(vp[2]);
                a3 += wj * bf2f(vp[3]);
            }
            __hip_bfloat16 ob[4] = {f2bf(a0), f2bf(a1), f2bf(a2), f2bf(a3)};
            *reinterpret_cast<short4v*>(atile + r * 264 + 4 * lane) =
                *reinterpret_cast<const short4v*>(ob);
        }
    }
    __syncthreads();

    // ---- outproj MFMA: wave wv -> cols [wv*32, wv*32+32); values stay in regs ----
    int lo = lane & 15, hi = lane >> 4;
    float val[2][4];
#pragma unroll
    for (int nt = 0; nt < 2; ++nt) {
        int n0 = wv * 32 + nt * 16;
        const __hip_bfloat16* arow = atile + lo * 264 + hi * 8;
        const __hip_bfloat16* brow = wout + (size_t)(n0 + lo) * E + hi * 8;
        f32x4 acc = {0.f, 0.f, 0.f, 0.f};
#pragma unroll
        for (int kk = 0; kk < 8; ++kk) {
            short8 a = *reinterpret_cast<const short8*>(arow + kk * 32);
            short8 b = *reinterpret_cast<const short8*>(brow + kk * 32);
            acc = __builtin_amdgcn_mfma_f32_16x16x32_bf16(a, b, acc, 0, 0, 0);
        }
        float bias = bout[n0 + lo];
#pragma unroll
        for (int r2 = 0; r2 < 4; ++r2) {
            int rowg = m0 + hi * 4 + r2;
            val[nt][r2] = acc[r2] + bias + resid[(size_t)rowg * E + n0 + lo];
        }
    }
    // per-row partial sums over this wave's 32-col stripe
    float s[4], s2[4];
#pragma unroll
    for (int r2 = 0; r2 < 4; ++r2) {
        s[r2]  = val[0][r2] + val[1][r2];
        s2[r2] = val[0][r2] * val[0][r2] + val[1][r2] * val[1][r2];
    }
#pragma unroll
    for (int off = 1; off < 16; off <<= 1) {
#pragma unroll
        for (int r2 = 0; r2 < 4; ++r2) {
            s[r2]  += __shfl_xor(s[r2], off);
            s2[r2] += __shfl_xor(s2[r2], off);
        }
    }
    if (lo == 0) {
#pragma unroll
        for (int r2 = 0; r2 < 4; ++r2) {
            lds_s[hi * 4 + r2][wv]  = s[r2];
            lds_s2[hi * 4 + r2][wv] = s2[r2];
        }
    }
    __syncthreads();
    if (wv == 0 && lane < 16) {
        float S = 0.f, S2 = 0.f;
#pragma unroll
        for (int w = 0; w < 8; ++w) { S += lds_s[lane][w]; S2 += lds_s2[lane][w]; }
        float mean = S * (1.f / 256.f);
        float var  = S2 * (1.f / 256.f) - mean * mean;
        lds_mv[lane] = mean;
        lds_rs[lane] = rsqrtf(var + 1e-5f);
    }
    __syncthreads();
#pragma unroll
    for (int nt = 0; nt < 2; ++nt) {
        int col = wv * 32 + nt * 16 + lo;
        float gg = lng[col], bb = lnb[col];
#pragma unroll
        for (int r2 = 0; r2 < 4; ++r2) {
            int row = hi * 4 + r2;
            float y = (val[nt][r2] - lds_mv[row]) * lds_rs[row] * gg + bb;
            outp[(size_t)(m0 + row) * E + col] = y;
        }
    }
}

extern "C" void kernel_launch(void* const* d_in, const int* in_sizes, int n_in,
                              void* d_out, int out_size, void* d_ws, size_t ws_size,
                              hipStream_t stream) {
    const int* rel = (const int*)d_in[0];
    const float* edge = (const float*)d_in[2];
    const float* face = (const float*)d_in[3];
    const float* w_in[2]  = {(const float*)d_in[4],  (const float*)d_in[10]};
    const float* b_in[2]  = {(const float*)d_in[5],  (const float*)d_in[11]};
    const float* w_out[2] = {(const float*)d_in[6],  (const float*)d_in[12]};
    const float* b_out[2] = {(const float*)d_in[7],  (const float*)d_in[13]};
    const float* ln_g[2]  = {(const float*)d_in[8],  (const float*)d_in[14]};
    const float* ln_b[2]  = {(const float*)d_in[9],  (const float*)d_in[15]};

    int S = in_sizes[2] / E;
    int L = in_sizes[3] / E;
    int ML = in_sizes[0] / L;

    char* ws = (char*)d_ws;
    __hip_bfloat16* edge16 = (__hip_bfloat16*)ws; ws += (size_t)S * E * 2;
    __hip_bfloat16* q16    = (__hip_bfloat16*)ws; ws += (size_t)L * E * 2;
    __hip_bfloat16* k16[2], *v16[2];
    for (int l = 0; l < 2; ++l) {
        k16[l] = (__hip_bfloat16*)ws; ws += (size_t)S * E * 2;
        v16[l] = (__hip_bfloat16*)ws; ws += (size_t)S * E * 2;
    }
    float* xres = (float*)ws;                     ws += (size_t)L * E * 4;
    __hip_bfloat16* win16[2], *wout16[2];
    for (int l = 0; l < 2; ++l) {
        win16[l]  = (__hip_bfloat16*)ws; ws += (size_t)3 * E * E * 2;
        wout16[l] = (__hip_bfloat16*)ws; ws += (size_t)E * E * 2;
    }

    float* outp = (float*)d_out;

    // 1) conversions: edge + weights (one launch)
    {
        CvtArgs ca;
        ca.in[0] = edge;     ca.out[0] = edge16;    ca.n[0] = S * E;
        ca.in[1] = w_in[0];  ca.out[1] = win16[0];  ca.n[1] = 3 * E * E;
        ca.in[2] = w_in[1];  ca.out[2] = win16[1];  ca.n[2] = 3 * E * E;
        ca.in[3] = w_out[0]; ca.out[3] = wout16[0]; ca.n[3] = E * E;
        ca.in[4] = w_out[1]; ca.out[4] = wout16[1]; ca.n[4] = E * E;
        int gx = (S * E) / (256 * 8);
        f2b_all<<<dim3(gx, 5), 256, 0, stream>>>(ca);
    }

    // 2) Q0 (fp32 A) + K0,V0,K1,V1 (bf16 A) projections — one launch, 5 segments
    {
        ProjArgs pa;
        pa.seg[0] = {face, nullptr,    win16[0],                     b_in[0],         q16};
        pa.seg[1] = {nullptr, edge16,  win16[0] + (size_t)E * E,     b_in[0] + E,     k16[0]};
        pa.seg[2] = {nullptr, edge16,  win16[0] + (size_t)2 * E * E, b_in[0] + 2 * E, v16[0]};
        pa.seg[3] = {nullptr, edge16,  win16[1] + (size_t)E * E,     b_in[1] + E,     k16[1]};
        pa.seg[4] = {nullptr, edge16,  win16[1] + (size_t)2 * E * E, b_in[1] + 2 * E, v16[1]};
        gemm_proj<<<dim3(L / 32, 5), 256, 0, stream>>>(pa, L);
    }

    // 3) layer 0: attn + outproj + LN -> xres (fp32)
    attn_outproj_ln<<<L / 16, 512, 0, stream>>>(rel, q16, k16[0], v16[0],
                                                wout16[0], b_out[0], face,
                                                ln_g[0], ln_b[0], xres, L, ML);

    // 4) Q1 projection from fp32 xres
    {
        ProjArgs pa;
        pa.seg[0] = {xres, nullptr, win16[1], b_in[1], q16};
        gemm_proj<<<dim3(L / 32, 1), 256, 0, stream>>>(pa, L);
    }

    // 5) layer 1: attn + outproj + LN -> d_out (fp32)
    attn_outproj_ln<<<L / 16, 512, 0, stream>>>(rel, q16, k16[1], v16[1],
                                                wout16[1], b_out[1], xres,
                                                ln_g[1], ln_b[1], outp, L, ML);
}

// Round 8
// 188.227 us; speedup vs baseline: 1.0111x; 1.0111x over previous
//
#include <hip/hip_runtime.h>
#include <hip/hip_bf16.h>

typedef short short8 __attribute__((ext_vector_type(8)));
typedef short short4v __attribute__((ext_vector_type(4)));
typedef float f32x4 __attribute__((ext_vector_type(4)));

#define E 256
#define DH 128

__device__ __forceinline__ float bf2f(__hip_bfloat16 x) { return __bfloat162float(x); }
__device__ __forceinline__ __hip_bfloat16 f2bf(float x) { return __float2bfloat16(x); }

__device__ __forceinline__ short8 cvt8(float4 a, float4 b) {
    __hip_bfloat16 t[8] = {f2bf(a.x), f2bf(a.y), f2bf(a.z), f2bf(a.w),
                           f2bf(b.x), f2bf(b.y), f2bf(b.z), f2bf(b.w)};
    return *reinterpret_cast<const short8*>(t);
}

// ---------- fused fp32 -> bf16 convert (edge + 4 weight arrays) ----------
struct CvtArgs { const float* in[5]; __hip_bfloat16* out[5]; int n[5]; };

__global__ __launch_bounds__(256) void f2b_all(CvtArgs a)
{
    int seg = blockIdx.y;
    int i = (blockIdx.x * 256 + threadIdx.x) * 8;
    if (i >= a.n[seg]) return;
    const float* in = a.in[seg];
    float4 x = *reinterpret_cast<const float4*>(in + i);
    float4 y = *reinterpret_cast<const float4*>(in + i + 4);
    *reinterpret_cast<short8*>(a.out[seg] + i) = cvt8(x, y);
}

// ---------- projection GEMM: out[M,256] = A[M,256] @ W^T + b (A fp32 or bf16) ----------
struct ProjSeg { const float* Af; const __hip_bfloat16* Ab;
                 const __hip_bfloat16* W; const float* b; __hip_bfloat16* out; };
struct ProjArgs { ProjSeg seg[5]; };

__global__ __launch_bounds__(256) void gemm_proj(ProjArgs args, int M)
{
    int wv = threadIdx.x >> 6, lane = threadIdx.x & 63;
    int m0 = blockIdx.x * 32;
    if (m0 >= M) return;
    ProjSeg sg = args.seg[blockIdx.y];
    int lo = lane & 15, hi = lane >> 4;

    const __hip_bfloat16* brow = sg.W + (size_t)(wv * 64 + lo) * E + hi * 8;

    f32x4 acc[2][4] = {};
    if (sg.Af) {
        const float* ar0 = sg.Af + (size_t)(m0 + lo) * E + hi * 8;
        const float* ar1 = ar0 + 16 * E;
#pragma unroll
        for (int k = 0; k < 8; ++k) {
            short8 a0 = cvt8(*reinterpret_cast<const float4*>(ar0 + k * 32),
                             *reinterpret_cast<const float4*>(ar0 + k * 32 + 4));
            short8 a1 = cvt8(*reinterpret_cast<const float4*>(ar1 + k * 32),
                             *reinterpret_cast<const float4*>(ar1 + k * 32 + 4));
#pragma unroll
            for (int nt = 0; nt < 4; ++nt) {
                short8 b = *reinterpret_cast<const short8*>(brow + (size_t)nt * 16 * E + k * 32);
                acc[0][nt] = __builtin_amdgcn_mfma_f32_16x16x32_bf16(a0, b, acc[0][nt], 0, 0, 0);
                acc[1][nt] = __builtin_amdgcn_mfma_f32_16x16x32_bf16(a1, b, acc[1][nt], 0, 0, 0);
            }
        }
    } else {
        const __hip_bfloat16* ar0 = sg.Ab + (size_t)(m0 + lo) * E + hi * 8;
        const __hip_bfloat16* ar1 = ar0 + 16 * E;
#pragma unroll
        for (int k = 0; k < 8; ++k) {
            short8 a0 = *reinterpret_cast<const short8*>(ar0 + k * 32);
            short8 a1 = *reinterpret_cast<const short8*>(ar1 + k * 32);
#pragma unroll
            for (int nt = 0; nt < 4; ++nt) {
                short8 b = *reinterpret_cast<const short8*>(brow + (size_t)nt * 16 * E + k * 32);
                acc[0][nt] = __builtin_amdgcn_mfma_f32_16x16x32_bf16(a0, b, acc[0][nt], 0, 0, 0);
                acc[1][nt] = __builtin_amdgcn_mfma_f32_16x16x32_bf16(a1, b, acc[1][nt], 0, 0, 0);
            }
        }
    }
#pragma unroll
    for (int nt = 0; nt < 4; ++nt) {
        int col = wv * 64 + nt * 16 + lo;
        float bias = sg.b[col];
#pragma unroll
        for (int mt = 0; mt < 2; ++mt)
#pragma unroll
            for (int r = 0; r < 4; ++r) {
                int row = m0 + mt * 16 + hi * 4 + r;
                sg.out[(size_t)row * E + col] = f2bf(acc[mt][nt][r] + bias);
            }
    }
}

// ---------- fused: sparse attn (16 faces, 1/wave) -> outproj MFMA (reg) -> LN ----------
// 1024 threads = 16 waves. Wave w: attention for face m0+w; then outproj col-stripe
// [w*16, w*16+16) held in registers; LN via cross-wave partial sums (2 KB LDS).
__global__ __launch_bounds__(1024) void attn_outproj_ln(
    const int* __restrict__ rel, const __hip_bfloat16* __restrict__ q16,
    const __hip_bfloat16* __restrict__ k16, const __hip_bfloat16* __restrict__ v16,
    const __hip_bfloat16* __restrict__ wout, const float* __restrict__ bout,
    const float* __restrict__ resid, const float* __restrict__ lng, const float* __restrict__ lnb,
    float* __restrict__ outp, int L, int ML)
{
    __shared__ __align__(16) __hip_bfloat16 atile[16 * 264];  // stride 264: 2-way banks (free)
    __shared__ __align__(16) float lds_w[16][2][16];          // [face][head][edge]
    __shared__ int lds_idx[16][16];
    __shared__ float lds_s[16][16], lds_s2[16][16];           // [row][wave]
    __shared__ float lds_mv[16], lds_rs[16];

    int tid = threadIdx.x, wv = tid >> 6, lane = tid & 63;
    int m0 = blockIdx.x * 16;
    int g = lane >> 2, q = lane & 3;
    int face = m0 + wv;
    const float scale = 0.088388347648318447f;  // 1/sqrt(128)

    // ---- attention: one face per wave ----
    const int* rr = rel + (size_t)face * ML;
    int myidx = (g < ML) ? rr[g] : -1;

    bool dup = false;
#pragma unroll
    for (int d = 1; d < 16; ++d) {
        int other = __shfl(myidx, ((g - d) & 15) * 4 + q);
        if (d <= g && other == myidx) dup = true;
    }
    bool myuse = (myidx >= 0) && !dup;       // set semantics: unique valid edges
    int safe = myidx < 0 ? 0 : myidx;
    if (q == 0) lds_idx[wv][g] = safe;

#pragma unroll
    for (int h = 0; h < 2; ++h) {
        const __hip_bfloat16* kbase = k16 + (size_t)safe * E + h * DH;
        const __hip_bfloat16* qbase = q16 + (size_t)face * E + h * DH;
        float part = 0.f;
#pragma unroll
        for (int t = 0; t < 4; ++t) {
            short8 qv = *reinterpret_cast<const short8*>(qbase + (t * 4 + q) * 8);
            short8 kv = *reinterpret_cast<const short8*>(kbase + (t * 4 + q) * 8);
            const __hip_bfloat16* qp = (const __hip_bfloat16*)&qv;
            const __hip_bfloat16* kp = (const __hip_bfloat16*)&kv;
#pragma unroll
            for (int e2 = 0; e2 < 8; ++e2)
                part += bf2f(qp[e2]) * bf2f(kp[e2]);
        }
        part += __shfl_xor(part, 1);
        part += __shfl_xor(part, 2);          // full 128-dim dot in all 4 quad lanes
        float sc = myuse ? part * scale : -1e30f;
        float mx = sc;
#pragma unroll
        for (int off = 4; off < 64; off <<= 1) mx = fmaxf(mx, __shfl_xor(mx, off));
        float e = __expf(sc - mx);            // exactly 0 for dead slots
        float den = e;
#pragma unroll
        for (int off = 4; off < 64; off <<= 1) den += __shfl_xor(den, off);
        if (q == 0) lds_w[wv][h][g] = e / den;
    }

    // V phase: lane covers dims [4*lane, 4*lane+4) of the 256-dim row
    {
        int h = lane >> 5;
        float a0 = 0.f, a1 = 0.f, a2 = 0.f, a3 = 0.f;
#pragma unroll
        for (int j = 0; j < 16; ++j) {
            int ij = lds_idx[wv][j];
            float wj = lds_w[wv][h][j];       // 0 for unused edges
            short4v vv = *reinterpret_cast<const short4v*>(v16 + (size_t)ij * E + 4 * lane);
            const __hip_bfloat16* vp = (const __hip_bfloat16*)&vv;
            a0 += wj * bf2f(vp[0]);
            a1 += wj * bf2f(vp[1]);
            a2 += wj * bf2f(vp[2]);
            a3 += wj * bf2f(vp[3]);
        }
        __hip_bfloat16 ob[4] = {f2bf(a0), f2bf(a1), f2bf(a2), f2bf(a3)};
        *reinterpret_cast<short4v*>(atile + wv * 264 + 4 * lane) =
            *reinterpret_cast<const short4v*>(ob);
    }
    __syncthreads();

    // ---- outproj MFMA: wave wv -> cols [wv*16, wv*16+16); values stay in regs ----
    int lo = lane & 15, hi = lane >> 4;
    float val[4];
    {
        const __hip_bfloat16* arow = atile + lo * 264 + hi * 8;
        const __hip_bfloat16* brow = wout + (size_t)(wv * 16 + lo) * E + hi * 8;
        f32x4 acc = {0.f, 0.f, 0.f, 0.f};
#pragma unroll
        for (int kk = 0; kk < 8; ++kk) {
            short8 a = *reinterpret_cast<const short8*>(arow + kk * 32);
            short8 b = *reinterpret_cast<const short8*>(brow + kk * 32);
            acc = __builtin_amdgcn_mfma_f32_16x16x32_bf16(a, b, acc, 0, 0, 0);
        }
        float bias = bout[wv * 16 + lo];
#pragma unroll
        for (int r2 = 0; r2 < 4; ++r2) {
            int rowg = m0 + hi * 4 + r2;
            val[r2] = acc[r2] + bias + resid[(size_t)rowg * E + wv * 16 + lo];
        }
    }
    // per-row partial sums across this wave's 16-col stripe (reduce over lo)
    float s[4], s2[4];
#pragma unroll
    for (int r2 = 0; r2 < 4; ++r2) { s[r2] = val[r2]; s2[r2] = val[r2] * val[r2]; }
#pragma unroll
    for (int off = 1; off < 16; off <<= 1) {
#pragma unroll
        for (int r2 = 0; r2 < 4; ++r2) {
            s[r2]  += __shfl_xor(s[r2], off);
            s2[r2] += __shfl_xor(s2[r2], off);
        }
    }
    if (lo == 0) {
#pragma unroll
        for (int r2 = 0; r2 < 4; ++r2) {
            lds_s[hi * 4 + r2][wv]  = s[r2];
            lds_s2[hi * 4 + r2][wv] = s2[r2];
        }
    }
    __syncthreads();
    if (wv == 0 && lane < 16) {
        float S = 0.f, S2 = 0.f;
#pragma unroll
        for (int w = 0; w < 16; ++w) { S += lds_s[lane][w]; S2 += lds_s2[lane][w]; }
        float mean = S * (1.f / 256.f);
        float var  = S2 * (1.f / 256.f) - mean * mean;
        lds_mv[lane] = mean;
        lds_rs[lane] = rsqrtf(var + 1e-5f);
    }
    __syncthreads();
    {
        int col = wv * 16 + lo;
        float gg = lng[col], bb = lnb[col];
#pragma unroll
        for (int r2 = 0; r2 < 4; ++r2) {
            int row = hi * 4 + r2;
            float y = (val[r2] - lds_mv[row]) * lds_rs[row] * gg + bb;
            outp[(size_t)(m0 + row) * E + col] = y;
        }
    }
}

extern "C" void kernel_launch(void* const* d_in, const int* in_sizes, int n_in,
                              void* d_out, int out_size, void* d_ws, size_t ws_size,
                              hipStream_t stream) {
    const int* rel = (const int*)d_in[0];
    const float* edge = (const float*)d_in[2];
    const float* face = (const float*)d_in[3];
    const float* w_in[2]  = {(const float*)d_in[4],  (const float*)d_in[10]};
    const float* b_in[2]  = {(const float*)d_in[5],  (const float*)d_in[11]};
    const float* w_out[2] = {(const float*)d_in[6],  (const float*)d_in[12]};
    const float* b_out[2] = {(const float*)d_in[7],  (const float*)d_in[13]};
    const float* ln_g[2]  = {(const float*)d_in[8],  (const float*)d_in[14]};
    const float* ln_b[2]  = {(const float*)d_in[9],  (const float*)d_in[15]};

    int S = in_sizes[2] / E;
    int L = in_sizes[3] / E;
    int ML = in_sizes[0] / L;

    char* ws = (char*)d_ws;
    __hip_bfloat16* edge16 = (__hip_bfloat16*)ws; ws += (size_t)S * E * 2;
    __hip_bfloat16* q16    = (__hip_bfloat16*)ws; ws += (size_t)L * E * 2;
    __hip_bfloat16* k16[2], *v16[2];
    for (int l = 0; l < 2; ++l) {
        k16[l] = (__hip_bfloat16*)ws; ws += (size_t)S * E * 2;
        v16[l] = (__hip_bfloat16*)ws; ws += (size_t)S * E * 2;
    }
    float* xres = (float*)ws;                     ws += (size_t)L * E * 4;
    __hip_bfloat16* win16[2], *wout16[2];
    for (int l = 0; l < 2; ++l) {
        win16[l]  = (__hip_bfloat16*)ws; ws += (size_t)3 * E * E * 2;
        wout16[l] = (__hip_bfloat16*)ws; ws += (size_t)E * E * 2;
    }

    float* outp = (float*)d_out;

    // 1) conversions: edge + weights (one launch)
    {
        CvtArgs ca;
        ca.in[0] = edge;     ca.out[0] = edge16;    ca.n[0] = S * E;
        ca.in[1] = w_in[0];  ca.out[1] = win16[0];  ca.n[1] = 3 * E * E;
        ca.in[2] = w_in[1];  ca.out[2] = win16[1];  ca.n[2] = 3 * E * E;
        ca.in[3] = w_out[0]; ca.out[3] = wout16[0]; ca.n[3] = E * E;
        ca.in[4] = w_out[1]; ca.out[4] = wout16[1]; ca.n[4] = E * E;
        int gx = (S * E) / (256 * 8);
        f2b_all<<<dim3(gx, 5), 256, 0, stream>>>(ca);
    }

    // 2) Q0 (fp32 A) + K0,V0,K1,V1 (bf16 A) projections — one launch, 5 segments
    {
        ProjArgs pa;
        pa.seg[0] = {face, nullptr,    win16[0],                     b_in[0],         q16};
        pa.seg[1] = {nullptr, edge16,  win16[0] + (size_t)E * E,     b_in[0] + E,     k16[0]};
        pa.seg[2] = {nullptr, edge16,  win16[0] + (size_t)2 * E * E, b_in[0] + 2 * E, v16[0]};
        pa.seg[3] = {nullptr, edge16,  win16[1] + (size_t)E * E,     b_in[1] + E,     k16[1]};
        pa.seg[4] = {nullptr, edge16,  win16[1] + (size_t)2 * E * E, b_in[1] + 2 * E, v16[1]};
        gemm_proj<<<dim3(L / 32, 5), 256, 0, stream>>>(pa, L);
    }

    // 3) layer 0: attn + outproj + LN -> xres (fp32)
    attn_outproj_ln<<<L / 16, 1024, 0, stream>>>(rel, q16, k16[0], v16[0],
                                                 wout16[0], b_out[0], face,
                                                 ln_g[0], ln_b[0], xres, L, ML);

    // 4) Q1 projection from fp32 xres
    {
        ProjArgs pa;
        pa.seg[0] = {xres, nullptr, win16[1], b_in[1], q16};
        gemm_proj<<<dim3(L / 32, 1), 256, 0, stream>>>(pa, L);
    }

    // 5) layer 1: attn + outproj + LN -> d_out (fp32)
    attn_outproj_ln<<<L / 16, 1024, 0, stream>>>(rel, q16, k16[1], v16[1],
                                                 wout16[1], b_out[1], xres,
                                                 ln_g[1], ln_b[1], outp, L, ML);
}